// Round 1
// 430.175 us; speedup vs baseline: 1.0505x; 1.0505x over previous
//
#include <hip/hip_runtime.h>

// Problem constants
#define Bn   4
#define Cc   256
#define Hh   128
#define Ww   256
#define HWp  32768          // H*W
#define CQK  64
#define COUT 256

typedef _Float16 half8 __attribute__((ext_vector_type(8)));
typedef _Float16 half4 __attribute__((ext_vector_type(4)));
typedef float   floatx4 __attribute__((ext_vector_type(4)));

#define MFMA16(a, b, c) __builtin_amdgcn_mfma_f32_16x16x32_f16((a), (b), (c), 0, 0, 0)

// ---------------------------------------------------------------------------
// Kernel 0: convert W (fp32) -> f16 once.  W16 layout: [Wq 64 | Wk 64 | Wv 256] x 256
// Stored in the tail of d_out (k_attn rewrites all of out afterwards).
// ---------------------------------------------------------------------------
__global__ __launch_bounds__(256) void k_wcvt(
    const float* __restrict__ Wq, const float* __restrict__ Wk,
    const float* __restrict__ Wv, _Float16* __restrict__ W16)
{
    const int e = (blockIdx.x * 256 + threadIdx.x) * 8;   // 0..98296
    const float* src;
    if (e < 16384)      src = Wq + e;
    else if (e < 32768) src = Wk + (e - 16384);
    else                src = Wv + (e - 32768);
    float4 f0 = *(const float4*)src;
    float4 f1 = *(const float4*)(src + 4);
    half8 h = {(_Float16)f0.x, (_Float16)f0.y, (_Float16)f0.z, (_Float16)f0.w,
               (_Float16)f1.x, (_Float16)f1.y, (_Float16)f1.z, (_Float16)f1.w};
    *(half8*)&W16[e] = h;
}

// x_lds column swizzle: conflict-free for both the 4px-transpose writes and the
// b-fragment half8 reads (verified bank arithmetic: 4 dwords/bank on writes,
// 8 lanes per 16B-slot on reads = hardware minimum for both).
__device__ __forceinline__ int xswz(int row) { return ((row ^ (row >> 2)) & 7) << 3; }

// ---------------------------------------------------------------------------
// Kernel 1: Q/K/V 1x1-conv projections.
//   Qws, Kws: pixel-major [b][pix][64];  Vws: channel-major [b][o][pix]
// grid: (512 pixel-tiles of 64, B, 2 jobs: 0=Q from de_out, 1=K+V from flow)
// W fragments are loaded per-lane from L2-hot f16 W16 (no w_lds, no inner
// barriers). x_lds swizzled. LDS = 32 KB -> 5 blocks/CU.
// ---------------------------------------------------------------------------
__global__ __launch_bounds__(256, 4) void k_qkv(
    const float* __restrict__ flow, const float* __restrict__ de_out,
    const _Float16* __restrict__ W16,
    const float* __restrict__ bq, const float* __restrict__ bk,
    const float* __restrict__ bv,
    _Float16* __restrict__ Qws, _Float16* __restrict__ Kws,
    _Float16* __restrict__ Vws)
{
    __shared__ __align__(16) _Float16 x_lds[64 * 256];   // [pix][c], swizzled

    const int t   = threadIdx.x;
    const int b   = blockIdx.y;
    const int job = blockIdx.z;
    const int pb  = blockIdx.x * 64;  // pixel base in [0, HW)

    const float* X = (job == 0 ? de_out : flow) + (size_t)b * Cc * HWp;

    // ---- stage X tile: [256 c][64 px] fp32 -> transposed f16 x_lds[px][c]
    {
        const int px4 = t & 15;   // pixel quad index
        const int cg  = t >> 4;   // 0..15
        #pragma unroll
        for (int rep = 0; rep < 4; ++rep) {
            const int c0 = 4 * cg + 64 * rep;
            float4 r0 = *(const float4*)&X[(size_t)(c0 + 0) * HWp + pb + 4 * px4];
            float4 r1 = *(const float4*)&X[(size_t)(c0 + 1) * HWp + pb + 4 * px4];
            float4 r2 = *(const float4*)&X[(size_t)(c0 + 2) * HWp + pb + 4 * px4];
            float4 r3 = *(const float4*)&X[(size_t)(c0 + 3) * HWp + pb + 4 * px4];
            const int r = 4 * px4;
            half4 h;
            h = (half4){(_Float16)r0.x, (_Float16)r1.x, (_Float16)r2.x, (_Float16)r3.x};
            *(half4*)&x_lds[(r + 0) * 256 + (c0 ^ xswz(r + 0))] = h;
            h = (half4){(_Float16)r0.y, (_Float16)r1.y, (_Float16)r2.y, (_Float16)r3.y};
            *(half4*)&x_lds[(r + 1) * 256 + (c0 ^ xswz(r + 1))] = h;
            h = (half4){(_Float16)r0.z, (_Float16)r1.z, (_Float16)r2.z, (_Float16)r3.z};
            *(half4*)&x_lds[(r + 2) * 256 + (c0 ^ xswz(r + 2))] = h;
            h = (half4){(_Float16)r0.w, (_Float16)r1.w, (_Float16)r2.w, (_Float16)r3.w};
            *(half4*)&x_lds[(r + 3) * 256 + (c0 ^ xswz(r + 3))] = h;
        }
    }
    __syncthreads();   // the only barrier in this kernel

    const int wv   = t >> 6;
    const int lane = t & 63;
    const int quad = lane >> 4;
    const int l16  = lane & 15;
    const int mrow = 16 * (wv & 1) + l16;
    const int n0   = (wv >> 1) * 32;
    const int nmt  = (job == 0) ? 2 : 10;

    const int rowb0 = n0 + l16;
    const int rowb1 = n0 + 16 + l16;
    const int sw0 = xswz(rowb0);
    const int sw1 = xswz(rowb1);

    for (int mt = 0; mt < nmt; ++mt) {
        int wbase, mbase, dstmode;
        const float* bsel;
        _Float16* dst;
        if (job == 0)     { wbase = 0;         mbase = mt * 32;       bsel = bq; dst = Qws; dstmode = 0; }
        else if (mt < 2)  { wbase = 64 * 256;  mbase = mt * 32;       bsel = bk; dst = Kws; dstmode = 0; }
        else              { wbase = 128 * 256; mbase = (mt - 2) * 32; bsel = bv; dst = Vws; dstmode = 1; }

        // A fragments straight from global f16 W (L2-hot, 16 rows x 64B coalesced)
        half8 a[8];
        #pragma unroll
        for (int ks = 0; ks < 8; ++ks)
            a[ks] = *(const half8*)&W16[wbase + (mbase + mrow) * 256 + ks * 32 + quad * 8];

        floatx4 acc0 = {0.f, 0.f, 0.f, 0.f};
        floatx4 acc1 = {0.f, 0.f, 0.f, 0.f};
        #pragma unroll
        for (int ks = 0; ks < 8; ++ks) {
            half8 b0 = *(const half8*)&x_lds[rowb0 * 256 + ((ks * 32 + quad * 8) ^ sw0)];
            half8 b1 = *(const half8*)&x_lds[rowb1 * 256 + ((ks * 32 + quad * 8) ^ sw1)];
            acc0 = MFMA16(a[ks], b0, acc0);
            acc1 = MFMA16(a[ks], b1, acc1);
        }

        // epilogue: D[row = quad*4+reg][col = l16], add bias, store f16
        const int mloc = 16 * (wv & 1) + quad * 4;
        float4 bi = *(const float4*)&bsel[mbase + mloc];
        const float bia[4] = {bi.x, bi.y, bi.z, bi.w};
        if (dstmode == 0) {
            #pragma unroll
            for (int nt = 0; nt < 2; ++nt) {
                floatx4 acc = nt ? acc1 : acc0;
                const int pix = pb + n0 + nt * 16 + l16;
                half4 h = (half4){(_Float16)(acc[0] + bia[0]), (_Float16)(acc[1] + bia[1]),
                                  (_Float16)(acc[2] + bia[2]), (_Float16)(acc[3] + bia[3])};
                *(half4*)&dst[((size_t)b * HWp + pix) * 64 + mbase + mloc] = h;
            }
        } else {
            #pragma unroll
            for (int nt = 0; nt < 2; ++nt) {
                floatx4 acc = nt ? acc1 : acc0;
                const int pix = pb + n0 + nt * 16 + l16;
                #pragma unroll
                for (int r = 0; r < 4; ++r) {
                    const int o = mbase + mloc + r;
                    dst[((size_t)b * 256 + o) * HWp + pix] = (_Float16)(acc[r] + bia[r]);
                }
            }
        }
    }
}

// ---------------------------------------------------------------------------
// Kernel 2: width-axial attention per (b,h) row.
// grid: (H, B), block 256 (4 waves).  K staged ONCE in swizzled LDS (32 KB);
// V held entirely in registers (32 x half8 per thread); q fragments direct
// from global.  att_lds swizzled, conflict-free. 3 barriers per chunk.
// ---------------------------------------------------------------------------
__global__ __launch_bounds__(256, 2) void k_attn(
    const _Float16* __restrict__ Qws, const _Float16* __restrict__ Kws,
    const _Float16* __restrict__ Vws, float* __restrict__ out)
{
    __shared__ __align__(16) _Float16 k_lds[256 * 64];    // [w'][d] swizzled, 32 KB
    __shared__ __align__(16) _Float16 att_lds[32 * 256];  // [w][w'] swizzled, 16 KB
    __shared__ float inv_l[32];

    const int t    = threadIdx.x;
    const int h    = blockIdx.x;
    const int b    = blockIdx.y;
    const int wv   = t >> 6;
    const int lane = t & 63;
    const int quad = lane >> 4;
    const int l16  = lane & 15;
    const size_t pixbase = (size_t)b * HWp + h * 256;

    // ---- V fragments into registers: o = os*64 + 16*wv + l16, w' chunk ks*32+quad*8
    half8 vf[4][8];
    #pragma unroll
    for (int os = 0; os < 4; ++os)
        #pragma unroll
        for (int ks = 0; ks < 8; ++ks)
            vf[os][ks] = *(const half8*)&Vws[((size_t)b * 256 + os * 64 + 16 * wv + l16) * HWp
                                             + h * 256 + ks * 32 + quad * 8];

    // ---- stage K once: 256 rows x 64 d, swizzled
    #pragma unroll
    for (int i = 0; i < 8; ++i) {
        const int g = t + 256 * i;
        const int row = g >> 3, off = (g & 7) * 8;
        *(half8*)&k_lds[row * 64 + (off ^ ((row & 7) << 3))] =
            *(const half8*)&Kws[(pixbase + row) * 64 + off];
    }
    __syncthreads();

    const int wt  = wv & 1;              // w-tile of this wave
    const int swq = (l16 & 7) << 3;      // row-parity swizzle (rows l16, 16+l16 share it)

    for (int chunk = 0; chunk < 8; ++chunk) {
        if (chunk) __syncthreads();      // protect att_lds/inv_l reuse

        // ---- energy, transposed: D[w'][w] = mfma(K-rows, Q-rows) -> att_lds[w][w']
        {
            const size_t qrow = pixbase + chunk * 32 + wt * 16 + l16;
            half8 bq0 = *(const half8*)&Qws[qrow * 64 + quad * 8];
            half8 bq1 = *(const half8*)&Qws[qrow * 64 + 32 + quad * 8];
            #pragma unroll
            for (int j = 0; j < 8; ++j) {
                const int nt = (wv >> 1) * 8 + j;      // w'-tile
                const int krow = nt * 16 + l16;
                half8 a0 = *(const half8*)&k_lds[krow * 64 + ((quad * 8) ^ swq)];
                half8 a1 = *(const half8*)&k_lds[krow * 64 + ((32 + quad * 8) ^ swq)];
                floatx4 acc = {0.f, 0.f, 0.f, 0.f};
                acc = MFMA16(a0, bq0, acc);
                acc = MFMA16(a1, bq1, acc);
                // D row = w'-local (quad*4+r), col = w-local (l16) -> half4 along w'
                half4 hv = (half4){(_Float16)acc[0], (_Float16)acc[1],
                                   (_Float16)acc[2], (_Float16)acc[3]};
                *(half4*)&att_lds[(wt * 16 + l16) * 256 + ((nt * 16 + quad * 4) ^ swq)] = hv;
            }
        }
        __syncthreads();

        // ---- softmax over w' (256), 8 threads per row, fp32 math
        {
            const int r = t >> 3, seg = t & 7;
            const int sw = (r & 7) << 3;
            _Float16* base = &att_lds[r * 256];
            half8 v[4];
            float mx = -1e30f;
            #pragma unroll
            for (int u = 0; u < 4; ++u) {
                v[u] = *(const half8*)&base[(seg * 32 + u * 8) ^ sw];
                #pragma unroll
                for (int e = 0; e < 8; ++e) mx = fmaxf(mx, (float)v[u][e]);
            }
            mx = fmaxf(mx, __shfl_xor(mx, 1));
            mx = fmaxf(mx, __shfl_xor(mx, 2));
            mx = fmaxf(mx, __shfl_xor(mx, 4));
            float s = 0.f;
            #pragma unroll
            for (int u = 0; u < 4; ++u) {
                half8 ex;
                #pragma unroll
                for (int e = 0; e < 8; ++e) {
                    const float p = __expf((float)v[u][e] - mx);
                    s += p;
                    ex[e] = (_Float16)p;
                }
                *(half8*)&base[(seg * 32 + u * 8) ^ sw] = ex;
            }
            s += __shfl_xor(s, 1);
            s += __shfl_xor(s, 2);
            s += __shfl_xor(s, 4);
            if (seg == 0) inv_l[r] = 1.f / s;
        }
        __syncthreads();

        // ---- PV: O[o][w] = sum_w' V[o][w'] * att[w][w'], V from registers
        {
            floatx4 acc[4][2];
            #pragma unroll
            for (int os = 0; os < 4; ++os) {
                acc[os][0] = (floatx4){0.f, 0.f, 0.f, 0.f};
                acc[os][1] = (floatx4){0.f, 0.f, 0.f, 0.f};
            }
            #pragma unroll
            for (int ks = 0; ks < 8; ++ks) {
                half8 p0 = *(const half8*)&att_lds[l16 * 256 + ((ks * 32 + quad * 8) ^ swq)];
                half8 p1 = *(const half8*)&att_lds[(16 + l16) * 256 + ((ks * 32 + quad * 8) ^ swq)];
                #pragma unroll
                for (int os = 0; os < 4; ++os) {
                    acc[os][0] = MFMA16(vf[os][ks], p0, acc[os][0]);
                    acc[os][1] = MFMA16(vf[os][ks], p1, acc[os][1]);
                }
            }
            const float il0 = inv_l[l16];
            const float il1 = inv_l[16 + l16];
            const int wg = chunk * 32 + l16;
            #pragma unroll
            for (int os = 0; os < 4; ++os) {
                const int og = os * 64 + 16 * wv + quad * 4;
                #pragma unroll
                for (int r = 0; r < 4; ++r) {
                    out[(((size_t)b * 256 + og + r) * Hh + h) * Ww + wg]      = acc[os][0][r] * il0;
                    out[(((size_t)b * 256 + og + r) * Hh + h) * Ww + 16 + wg] = acc[os][1][r] * il1;
                }
            }
        }
    }
}

// ---------------------------------------------------------------------------
extern "C" void kernel_launch(void* const* d_in, const int* in_sizes, int n_in,
                              void* d_out, int out_size, void* d_ws, size_t ws_size,
                              hipStream_t stream)
{
    const float* flow   = (const float*)d_in[0];
    const float* de_out = (const float*)d_in[1];
    const float* Wq = (const float*)d_in[2];
    const float* bq = (const float*)d_in[3];
    const float* Wk = (const float*)d_in[4];
    const float* bk = (const float*)d_in[5];
    const float* Wv = (const float*)d_in[6];
    const float* bv = (const float*)d_in[7];

    _Float16* Qws = (_Float16*)d_ws;
    _Float16* Kws = Qws + (size_t)Bn * HWp * 64;
    _Float16* Vws = Kws + (size_t)Bn * HWp * 64;
    float* out = (float*)d_out;

    // f16 weights live in the tail of d_out (384*256 halves = 192 KB);
    // k_attn overwrites every element of out afterwards, so this is scratch.
    _Float16* W16 = (_Float16*)((char*)d_out + (size_t)out_size - 98304 * sizeof(_Float16));

    k_wcvt<<<dim3(48), 256, 0, stream>>>(Wq, Wk, Wv, W16);

    dim3 g1(HWp / 64, Bn, 2);
    k_qkv<<<g1, 256, 0, stream>>>(flow, de_out, W16, bq, bk, bv, Qws, Kws, Vws);

    dim3 g2(Hh, Bn);
    k_attn<<<g2, 256, 0, stream>>>(Qws, Kws, Vws, out);
}